// Round 1
// baseline (14557.982 us; speedup 1.0000x reference)
//
#include <hip/hip_runtime.h>
#include <math.h>

// ---------------------------------------------------------------------------
// MGRU (BRITS-style) forward. Structure:
//   precompute (input-only, big batched GEMMs over T*B rows):
//     gamma_x_all[t,b,F], gamma_h_all[t,b,H], beta_all[t,b,F]
//   per step t (sequential over hid):
//     P1: x_hat = hid @ Wout^T + bout
//     P2: z_hat = x_c @ Wz'^T + bz ; c_hat, c_c, losses 1/2/3 (atomics)
//     P3: fused GRU gates (6 dot families) + hid_next = GRU(...) * gamma_h[t+1]
//   final: loss = sum_t (n1+n2+n3)/(den+1e-5)
// hid double-buffered; c_c read back from d_out by P3.
// ---------------------------------------------------------------------------

#define F_DIM 256
#define H_DIM 512
#define B_DIM 512
#define T_DIM 128
#define TF    (T_DIM * F_DIM)          // 32768
#define S3TF  (3 * TF)                 // 98304 (per-b stride of input)
#define BTFsz ((size_t)B_DIM * T_DIM * F_DIM)  // 16777216

// ---------------------------------------------------------------- init / den
__global__ void init_k(float* __restrict__ hidA, float* __restrict__ num) {
    int i = blockIdx.x * 256 + threadIdx.x;
    if (i < B_DIM * H_DIM) hidA[i] = 0.f;
    if (i < 3 * T_DIM) num[i] = 0.f;
}

__global__ void den_k(const float* __restrict__ inp, float* __restrict__ den) {
    int t = blockIdx.x, tid = threadIdx.x;
    float s = 0.f;
    for (int i = tid; i < B_DIM * F_DIM; i += 256) {
        int b = i >> 8, f = i & 255;
        s += inp[(size_t)b * S3TF + 2 * TF + (size_t)t * F_DIM + f];
    }
    __shared__ float red[256];
    red[tid] = s; __syncthreads();
    for (int o = 128; o > 0; o >>= 1) { if (tid < o) red[tid] += red[tid + o]; __syncthreads(); }
    if (tid == 0) den[t] = red[0];
}

// ------------------------------------------------- 64x64x16 fp32 GEMM bodies
#define FMA16(ACC, A4, B4)                                                 \
    ACC[0][0] += A4.x * B4.x; ACC[0][1] += A4.x * B4.y;                    \
    ACC[0][2] += A4.x * B4.z; ACC[0][3] += A4.x * B4.w;                    \
    ACC[1][0] += A4.y * B4.x; ACC[1][1] += A4.y * B4.y;                    \
    ACC[1][2] += A4.y * B4.z; ACC[1][3] += A4.y * B4.w;                    \
    ACC[2][0] += A4.z * B4.x; ACC[2][1] += A4.z * B4.y;                    \
    ACC[2][2] += A4.z * B4.z; ACC[2][3] += A4.z * B4.w;                    \
    ACC[3][0] += A4.w * B4.x; ACC[3][1] += A4.w * B4.y;                    \
    ACC[3][2] += A4.w * B4.z; ACC[3][3] += A4.w * B4.w;

// gamma_{x,h}[t,b,n] = exp(-relu(d[t,b,:] @ W[n,:] + bias[n]))  (K = F_DIM)
template <int N_DIM>
__global__ __launch_bounds__(256) void decay_gemm(const float* __restrict__ inp,
                                                  const float* __restrict__ W,
                                                  const float* __restrict__ bias,
                                                  float* __restrict__ out) {
    __shared__ float As[16][64];
    __shared__ float Bs[16][64];
    const int tid = threadIdx.x;
    const int row0 = blockIdx.x * 64, n0 = blockIdx.y * 64;
    const int lm = tid >> 2, lk = (tid & 3) * 4;
    const int arow = row0 + lm, tt = arow >> 9, bb = arow & 511;
    const float* aptr = inp + (size_t)bb * S3TF + TF + (size_t)tt * F_DIM; // delta row
    const float* bptr = W + (size_t)(n0 + lm) * F_DIM;
    const int mb = (tid >> 4) * 4, nb = (tid & 15) * 4;
    float acc[4][4] = {};
    for (int k0 = 0; k0 < F_DIM; k0 += 16) {
        float4 av = *(const float4*)(aptr + k0 + lk);
        float4 bv = *(const float4*)(bptr + k0 + lk);
        As[lk][lm] = av.x; As[lk + 1][lm] = av.y; As[lk + 2][lm] = av.z; As[lk + 3][lm] = av.w;
        Bs[lk][lm] = bv.x; Bs[lk + 1][lm] = bv.y; Bs[lk + 2][lm] = bv.z; Bs[lk + 3][lm] = bv.w;
        __syncthreads();
#pragma unroll
        for (int kk = 0; kk < 16; ++kk) {
            float4 a = *(const float4*)&As[kk][mb];
            float4 b = *(const float4*)&Bs[kk][nb];
            FMA16(acc, a, b)
        }
        __syncthreads();
    }
#pragma unroll
    for (int i = 0; i < 4; ++i) {
        size_t r = row0 + mb + i;
#pragma unroll
        for (int j = 0; j < 4; ++j) {
            int n = n0 + nb + j;
            out[r * N_DIM + n] = expf(-fmaxf(acc[i][j] + bias[n], 0.f));
        }
    }
}

// beta[t,b,n] = [gamma_x, m] @ Wbeta[n,:] + bbeta[n]   (K = 2F)
__global__ __launch_bounds__(256) void beta_gemm(const float* __restrict__ inp,
                                                 const float* __restrict__ gx,
                                                 const float* __restrict__ Wb,
                                                 const float* __restrict__ bias,
                                                 float* __restrict__ out) {
    __shared__ float As[16][64];
    __shared__ float Bs[16][64];
    const int tid = threadIdx.x;
    const int row0 = blockIdx.x * 64, n0 = blockIdx.y * 64;
    const int lm = tid >> 2, lk = (tid & 3) * 4;
    const int arow = row0 + lm, tt = arow >> 9, bb = arow & 511;
    const float* mrow = inp + (size_t)bb * S3TF + 2 * TF + (size_t)tt * F_DIM;
    const float* gxrow = gx + (size_t)arow * F_DIM;
    const float* bptr = Wb + (size_t)(n0 + lm) * (2 * F_DIM);
    const int mb = (tid >> 4) * 4, nb = (tid & 15) * 4;
    float acc[4][4] = {};
    for (int k0 = 0; k0 < 2 * F_DIM; k0 += 16) {
        int kg = k0 + lk;
        float4 av = (kg < F_DIM) ? *(const float4*)(gxrow + kg)
                                 : *(const float4*)(mrow + (kg - F_DIM));
        float4 bv = *(const float4*)(bptr + kg);
        As[lk][lm] = av.x; As[lk + 1][lm] = av.y; As[lk + 2][lm] = av.z; As[lk + 3][lm] = av.w;
        Bs[lk][lm] = bv.x; Bs[lk + 1][lm] = bv.y; Bs[lk + 2][lm] = bv.z; Bs[lk + 3][lm] = bv.w;
        __syncthreads();
#pragma unroll
        for (int kk = 0; kk < 16; ++kk) {
            float4 a = *(const float4*)&As[kk][mb];
            float4 b = *(const float4*)&Bs[kk][nb];
            FMA16(acc, a, b)
        }
        __syncthreads();
    }
#pragma unroll
    for (int i = 0; i < 4; ++i) {
        size_t r = row0 + mb + i;
#pragma unroll
        for (int j = 0; j < 4; ++j) {
            int n = n0 + nb + j;
            out[r * F_DIM + n] = acc[i][j] + bias[n];
        }
    }
}

// ----------------------------------------------------- P1: x_hat (32x32x32)
__global__ __launch_bounds__(256) void p1_xhat(const float* __restrict__ hid,
                                               const float* __restrict__ Wout,
                                               const float* __restrict__ bout,
                                               float* __restrict__ xhat) {
    __shared__ float As[32][32];
    __shared__ float Bs[32][32];
    const int tid = threadIdx.x;
    const int b0 = blockIdx.x * 32, n0 = blockIdx.y * 32;
    const int am = tid >> 3, ak = (tid & 7) * 4;
    const int mb = (tid >> 4) * 2, nb = (tid & 15) * 2;
    float acc[2][2] = {};
    for (int k0 = 0; k0 < H_DIM; k0 += 32) {
        float4 av = *(const float4*)(hid + (size_t)(b0 + am) * H_DIM + k0 + ak);
        float4 bv = *(const float4*)(Wout + (size_t)(n0 + am) * H_DIM + k0 + ak);
        As[ak][am] = av.x; As[ak + 1][am] = av.y; As[ak + 2][am] = av.z; As[ak + 3][am] = av.w;
        Bs[ak][am] = bv.x; Bs[ak + 1][am] = bv.y; Bs[ak + 2][am] = bv.z; Bs[ak + 3][am] = bv.w;
        __syncthreads();
#pragma unroll
        for (int kk = 0; kk < 32; ++kk) {
            float2 a = *(const float2*)&As[kk][mb];
            float2 b = *(const float2*)&Bs[kk][nb];
            acc[0][0] += a.x * b.x; acc[0][1] += a.x * b.y;
            acc[1][0] += a.y * b.x; acc[1][1] += a.y * b.y;
        }
        __syncthreads();
    }
#pragma unroll
    for (int i = 0; i < 2; ++i)
#pragma unroll
        for (int j = 0; j < 2; ++j)
            xhat[(size_t)(b0 + mb + i) * F_DIM + n0 + nb + j] = acc[i][j] + bout[n0 + nb + j];
}

// ---------------------- P2: z_hat / c_hat / c_c + loss numerators (32x32x32)
__global__ __launch_bounds__(256) void p2_impute(const float* __restrict__ inp,
                                                 const float* __restrict__ xhat,
                                                 const float* __restrict__ Wz,
                                                 const float* __restrict__ bz,
                                                 const float* __restrict__ beta,
                                                 float* __restrict__ out,
                                                 float* __restrict__ num, int t) {
    __shared__ float As[32][32];
    __shared__ float Bs[32][32];
    __shared__ float red[256];
    const int tid = threadIdx.x;
    const int b0 = blockIdx.x * 32, n0 = blockIdx.y * 32;
    const int am = tid >> 3, ak = (tid & 7) * 4;
    const int mb = (tid >> 4) * 2, nb = (tid & 15) * 2;
    float acc[2][2] = {};
    for (int k0 = 0; k0 < F_DIM; k0 += 32) {
        // x_c tile: m*v + (1-m)*x_hat
        {
            int b = b0 + am;
            const float* vrow = inp + (size_t)b * S3TF + (size_t)t * F_DIM;
            float4 v4 = *(const float4*)(vrow + k0 + ak);
            float4 m4 = *(const float4*)(vrow + 2 * TF + k0 + ak);
            float4 x4 = *(const float4*)(xhat + (size_t)b * F_DIM + k0 + ak);
            As[ak][am]     = m4.x * v4.x + (1.f - m4.x) * x4.x;
            As[ak + 1][am] = m4.y * v4.y + (1.f - m4.y) * x4.y;
            As[ak + 2][am] = m4.z * v4.z + (1.f - m4.z) * x4.z;
            As[ak + 3][am] = m4.w * v4.w + (1.f - m4.w) * x4.w;
        }
        // Wz tile with zero diagonal
        {
            int f = n0 + am;
            float4 w4 = *(const float4*)(Wz + (size_t)f * F_DIM + k0 + ak);
            Bs[ak][am]     = (k0 + ak     == f) ? 0.f : w4.x;
            Bs[ak + 1][am] = (k0 + ak + 1 == f) ? 0.f : w4.y;
            Bs[ak + 2][am] = (k0 + ak + 2 == f) ? 0.f : w4.z;
            Bs[ak + 3][am] = (k0 + ak + 3 == f) ? 0.f : w4.w;
        }
        __syncthreads();
#pragma unroll
        for (int kk = 0; kk < 32; ++kk) {
            float2 a = *(const float2*)&As[kk][mb];
            float2 b = *(const float2*)&Bs[kk][nb];
            acc[0][0] += a.x * b.x; acc[0][1] += a.x * b.y;
            acc[1][0] += a.y * b.x; acc[1][1] += a.y * b.y;
        }
        __syncthreads();
    }
    float l1 = 0.f, l2 = 0.f, l3 = 0.f;
#pragma unroll
    for (int i = 0; i < 2; ++i) {
        int b = b0 + mb + i;
        const float* vrow = inp + (size_t)b * S3TF + (size_t)t * F_DIM;
#pragma unroll
        for (int j = 0; j < 2; ++j) {
            int f = n0 + nb + j;
            float zh = acc[i][j] + bz[f];
            float xh = xhat[(size_t)b * F_DIM + f];
            float bt = beta[((size_t)t * B_DIM + b) * F_DIM + f];
            float ch = bt * zh + (1.f - bt) * xh;
            float v = vrow[f], m = vrow[2 * TF + f];
            float cc = m * v + (1.f - m) * ch;
            out[(size_t)b * TF + (size_t)t * F_DIM + f] = ch;
            out[BTFsz + (size_t)b * TF + (size_t)t * F_DIM + f] = cc;
            l1 += fabsf(v - xh) * m;
            l2 += fabsf(v - zh) * m;
            l3 += fabsf(v - ch) * m;
        }
    }
    red[tid] = l1; __syncthreads();
    for (int o = 128; o > 0; o >>= 1) { if (tid < o) red[tid] += red[tid + o]; __syncthreads(); }
    if (tid == 0) atomicAdd(&num[t], red[0]);
    __syncthreads();
    red[tid] = l2; __syncthreads();
    for (int o = 128; o > 0; o >>= 1) { if (tid < o) red[tid] += red[tid + o]; __syncthreads(); }
    if (tid == 0) atomicAdd(&num[T_DIM + t], red[0]);
    __syncthreads();
    red[tid] = l3; __syncthreads();
    for (int o = 128; o > 0; o >>= 1) { if (tid < o) red[tid] += red[tid + o]; __syncthreads(); }
    if (tid == 0) atomicAdd(&num[2 * T_DIM + t], red[0]);
}

// ------------------- P3: fused GRU gates + hid update (64 b x 16 j, K = 512)
__global__ __launch_bounds__(256) void p3_gru(const float* __restrict__ inp,
                                              const float* __restrict__ out,  // c_c source
                                              const float* __restrict__ hid,
                                              const float* __restrict__ Wih,
                                              const float* __restrict__ Whh,
                                              const float* __restrict__ bih,
                                              const float* __restrict__ bhh,
                                              const float* __restrict__ gh,
                                              float* __restrict__ hidn, int t) {
    __shared__ float Ag[32][64];
    __shared__ float Ah[32][64];
    __shared__ float Bsm[6][16][32];   // [family][j][k]
    const int tid = threadIdx.x;
    const int b0 = blockIdx.x * 64, j0 = blockIdx.y * 16;
    const int lm = tid >> 2, lk = (tid & 3) * 4;    // A loader: 64 rows x 16 k (x2 passes)
    const int jr = tid >> 4, kc = (tid & 15) * 2;   // B loader: 16 j x 32 k, float2
    const int mb = (tid >> 4) * 4, jn = tid & 15;
    float aglr[4] = {}, aglz[4] = {}, agln[4] = {};
    float ahlr[4] = {}, ahlz[4] = {}, ahln[4] = {};
    const int b_a = b0 + lm;
    const float* ccrow = out + BTFsz + (size_t)b_a * TF + (size_t)t * F_DIM;
    const float* mrow  = inp + (size_t)b_a * S3TF + 2 * TF + (size_t)t * F_DIM;
    const float* hrow  = hid + (size_t)b_a * H_DIM;
    for (int k0 = 0; k0 < 512; k0 += 32) {
#pragma unroll
        for (int h = 0; h < 2; ++h) {
            int kg = k0 + lk + h * 16;
            float4 g4 = (kg < F_DIM) ? *(const float4*)(ccrow + kg)
                                     : *(const float4*)(mrow + (kg - F_DIM));
            float4 h4 = *(const float4*)(hrow + kg);
            int ks = lk + h * 16;
            Ag[ks][lm] = g4.x; Ag[ks + 1][lm] = g4.y; Ag[ks + 2][lm] = g4.z; Ag[ks + 3][lm] = g4.w;
            Ah[ks][lm] = h4.x; Ah[ks + 1][lm] = h4.y; Ah[ks + 2][lm] = h4.z; Ah[ks + 3][lm] = h4.w;
        }
        {
            size_t rj = (size_t)(j0 + jr);
            const float* w0 = Wih + rj * 512 + k0 + kc;
            const float* w1 = Wih + (H_DIM + rj) * 512 + k0 + kc;
            const float* w2 = Wih + (2 * H_DIM + rj) * 512 + k0 + kc;
            const float* w3 = Whh + rj * 512 + k0 + kc;
            const float* w4 = Whh + (H_DIM + rj) * 512 + k0 + kc;
            const float* w5 = Whh + (2 * H_DIM + rj) * 512 + k0 + kc;
            *(float2*)&Bsm[0][jr][kc] = *(const float2*)w0;
            *(float2*)&Bsm[1][jr][kc] = *(const float2*)w1;
            *(float2*)&Bsm[2][jr][kc] = *(const float2*)w2;
            *(float2*)&Bsm[3][jr][kc] = *(const float2*)w3;
            *(float2*)&Bsm[4][jr][kc] = *(const float2*)w4;
            *(float2*)&Bsm[5][jr][kc] = *(const float2*)w5;
        }
        __syncthreads();
#pragma unroll 8
        for (int kk = 0; kk < 32; ++kk) {
            float4 g = *(const float4*)&Ag[kk][mb];
            float4 h = *(const float4*)&Ah[kk][mb];
            float w0 = Bsm[0][jn][kk], w1 = Bsm[1][jn][kk], w2 = Bsm[2][jn][kk];
            float w3 = Bsm[3][jn][kk], w4 = Bsm[4][jn][kk], w5 = Bsm[5][jn][kk];
            aglr[0] += g.x * w0; aglr[1] += g.y * w0; aglr[2] += g.z * w0; aglr[3] += g.w * w0;
            aglz[0] += g.x * w1; aglz[1] += g.y * w1; aglz[2] += g.z * w1; aglz[3] += g.w * w1;
            agln[0] += g.x * w2; agln[1] += g.y * w2; agln[2] += g.z * w2; agln[3] += g.w * w2;
            ahlr[0] += h.x * w3; ahlr[1] += h.y * w3; ahlr[2] += h.z * w3; ahlr[3] += h.w * w3;
            ahlz[0] += h.x * w4; ahlz[1] += h.y * w4; ahlz[2] += h.z * w4; ahlz[3] += h.w * w4;
            ahln[0] += h.x * w5; ahln[1] += h.y * w5; ahln[2] += h.z * w5; ahln[3] += h.w * w5;
        }
        __syncthreads();
    }
    const int j = j0 + jn;
    const float br = bih[j], bz2 = bih[H_DIM + j], bn = bih[2 * H_DIM + j];
    const float cr = bhh[j], cz = bhh[H_DIM + j], cn = bhh[2 * H_DIM + j];
#pragma unroll
    for (int i = 0; i < 4; ++i) {
        int b = b0 + mb + i;
        float r = 1.f / (1.f + expf(-(aglr[i] + br + ahlr[i] + cr)));
        float z = 1.f / (1.f + expf(-(aglz[i] + bz2 + ahlz[i] + cz)));
        float n = tanhf(agln[i] + bn + r * (ahln[i] + cn));
        float hold = hid[(size_t)b * H_DIM + j];
        float hnew = (1.f - z) * n + z * hold;
        if (t + 1 < T_DIM) hnew *= gh[((size_t)(t + 1) * B_DIM + b) * H_DIM + j];
        hidn[(size_t)b * H_DIM + j] = hnew;
    }
}

// ----------------------------------------------------------------- final loss
__global__ void final_k(const float* __restrict__ num, const float* __restrict__ den,
                        float* __restrict__ outloss) {
    int tid = threadIdx.x;  // 128 threads, one per t
    float v = (num[tid] + num[T_DIM + tid] + num[2 * T_DIM + tid]) / (den[tid] + 1e-5f);
    __shared__ float red[128];
    red[tid] = v; __syncthreads();
    for (int o = 64; o > 0; o >>= 1) { if (tid < o) red[tid] += red[tid + o]; __syncthreads(); }
    if (tid == 0) *outloss = red[0];
}

// ---------------------------------------------------------------------------
extern "C" void kernel_launch(void* const* d_in, const int* in_sizes, int n_in,
                              void* d_out, int out_size, void* d_ws, size_t ws_size,
                              hipStream_t stream) {
    const float* inp   = (const float*)d_in[0];
    const float* Wdx   = (const float*)d_in[1];
    const float* bdx   = (const float*)d_in[2];
    const float* Wdh   = (const float*)d_in[3];
    const float* bdh   = (const float*)d_in[4];
    const float* Wout  = (const float*)d_in[5];
    const float* bout  = (const float*)d_in[6];
    const float* Wz    = (const float*)d_in[7];
    const float* bz    = (const float*)d_in[8];
    const float* Wbeta = (const float*)d_in[9];
    const float* bbeta = (const float*)d_in[10];
    const float* Wih   = (const float*)d_in[11];
    const float* Whh   = (const float*)d_in[12];
    const float* bih   = (const float*)d_in[13];
    const float* bhh   = (const float*)d_in[14];
    float* out = (float*)d_out;

    float* ws = (float*)d_ws;
    size_t off = 0;
    float* gh   = ws + off; off += (size_t)T_DIM * B_DIM * H_DIM;  // 33.5M
    float* gx   = ws + off; off += (size_t)T_DIM * B_DIM * F_DIM;  // 16.8M
    float* beta = ws + off; off += (size_t)T_DIM * B_DIM * F_DIM;  // 16.8M
    float* hidA = ws + off; off += (size_t)B_DIM * H_DIM;
    float* hidB = ws + off; off += (size_t)B_DIM * H_DIM;
    float* xhat = ws + off; off += (size_t)B_DIM * F_DIM;
    float* num  = ws + off; off += 3 * T_DIM;
    float* den  = ws + off; off += T_DIM;

    init_k<<<dim3((B_DIM * H_DIM + 255) / 256), 256, 0, stream>>>(hidA, num);
    den_k<<<dim3(T_DIM), 256, 0, stream>>>(inp, den);
    decay_gemm<F_DIM><<<dim3(1024, F_DIM / 64), 256, 0, stream>>>(inp, Wdx, bdx, gx);
    decay_gemm<H_DIM><<<dim3(1024, H_DIM / 64), 256, 0, stream>>>(inp, Wdh, bdh, gh);
    beta_gemm<<<dim3(1024, F_DIM / 64), 256, 0, stream>>>(inp, gx, Wbeta, bbeta, beta);

    for (int t = 0; t < T_DIM; ++t) {
        float* hc = (t & 1) ? hidB : hidA;
        float* hn = (t & 1) ? hidA : hidB;
        p1_xhat<<<dim3(16, 8), 256, 0, stream>>>(hc, Wout, bout, xhat);
        p2_impute<<<dim3(16, 8), 256, 0, stream>>>(inp, xhat, Wz, bz, beta, out, num, t);
        p3_gru<<<dim3(8, 32), 256, 0, stream>>>(inp, out, hc, Wih, Whh, bih, bhh, gh, hn, t);
    }
    final_k<<<dim3(1), 128, 0, stream>>>(num, den, out + 2 * BTFsz);
}

// Round 2
// 5454.767 us; speedup vs baseline: 2.6689x; 2.6689x over previous
//
#include <hip/hip_runtime.h>
#include <math.h>

// ---------------------------------------------------------------------------
// MGRU (BRITS-style) forward, bf16 MFMA version.
//   precompute: weight/activation bf16 conversion; gamma_x, gamma_h, beta via
//               big MFMA GEMMs over T*B = 65536 rows.
//   per step t: K1 x_hat GEMM (+loss1, x_c bf16), K2 z_hat GEMM (+c_hat/c_c,
//               loss2/3, gi=[c_c|m] bf16), K3 fused 6-family GRU GEMM + gates.
//   No LDS in GEMMs: MFMA frags loaded directly from global (L1/L2-hot B).
//   Frag layouts (m89/m91-verified): A[m=lane&15][k=(lane>>4)*8+i],
//   B[k][n]: n=lane&15, k=(lane>>4)*8+i ; C/D: col=lane&15, row=(lane>>4)*4+reg.
// ---------------------------------------------------------------------------

#define F 256
#define H 512
#define B 512
#define T 128
#define TF 32768          // T*F
#define S3TF 98304        // 3*T*F
#define BTF ((size_t)B * T * F)

typedef __attribute__((ext_vector_type(8))) short bf8;
typedef __attribute__((ext_vector_type(4))) float f4;
#define MFMA16 __builtin_amdgcn_mfma_f32_16x16x32_bf16

__device__ inline short f2bf(float x) {
    unsigned u = __builtin_bit_cast(unsigned, x);
    u += 0x7fff + ((u >> 16) & 1);
    return (short)(u >> 16);
}
__device__ inline float bf2f(short s) {
    unsigned u = ((unsigned)(unsigned short)s) << 16;
    return __builtin_bit_cast(float, u);
}
__device__ inline float wsum(float v) {
#pragma unroll
    for (int o = 32; o > 0; o >>= 1) v += __shfl_down(v, o, 64);
    return v;
}

// --------------------------------------------------------------------- init
__global__ void init_k(float* __restrict__ hf, short* __restrict__ hb,
                       float* __restrict__ nd) {
    int i = blockIdx.x * 256 + threadIdx.x;   // 262144 = B*H
    hf[i] = 0.f; hb[i] = 0;
    if (i < 512) nd[i] = 0.f;                 // num[384] + den[128]
}

// ------------------------------------------------------- weight conversion
__global__ void wconv_k(const float* __restrict__ Wdx, const float* __restrict__ Wdh,
                        const float* __restrict__ Wz, const float* __restrict__ Wout,
                        const float* __restrict__ Wbeta, const float* __restrict__ Wih,
                        const float* __restrict__ Whh, short* __restrict__ wb) {
    int i = blockIdx.x * 256 + threadIdx.x;   // 2097152 total
    float v;
    if (i < 65536) v = Wdx[i];
    else if (i < 196608) v = Wdh[i - 65536];
    else if (i < 262144) { int l = i - 196608; v = ((l >> 8) == (l & 255)) ? 0.f : Wz[l]; }
    else if (i < 393216) v = Wout[i - 262144];
    else if (i < 524288) v = Wbeta[i - 393216];
    else if (i < 1310720) v = Wih[i - 524288];
    else v = Whh[i - 1310720];
    wb[i] = f2bf(v);
}

// --------------------------------------- activation conversion + den[t]
__global__ void aconv_k(const float* __restrict__ inp, short* __restrict__ dbf,
                        short* __restrict__ abf, float* __restrict__ den) {
    int i = blockIdx.x * 256 + threadIdx.x;   // 16777216 ; block = one (t,b) row
    int r = i >> 8, f = i & 255;
    int t = r >> 9, b = r & 511;
    const float* base = inp + (size_t)b * S3TF + (size_t)t * F;
    dbf[i] = f2bf(base[TF + f]);
    float m = base[2 * TF + f];
    abf[(size_t)r * 512 + 256 + f] = f2bf(m);   // m half of [gamma_x | m]
    float s = wsum(m);
    __shared__ float red[4];
    if ((threadIdx.x & 63) == 0) red[threadIdx.x >> 6] = s;
    __syncthreads();
    if (threadIdx.x == 0) atomicAdd(&den[t], red[0] + red[1] + red[2] + red[3]);
}

// ---------------------------------- precompute GEMMs (M=65536 rows, no LDS)
__global__ __launch_bounds__(256) void gx_gemm(const short* __restrict__ A,
                                               const short* __restrict__ W,
                                               const float* __restrict__ bias,
                                               short* __restrict__ abf) {
    int gw = blockIdx.x * 4 + (threadIdx.x >> 6);   // 65536 wave-tiles
    int lane = threadIdx.x & 63, l16 = lane & 15, quad = lane >> 4;
    int r0 = (gw >> 4) * 16, n0 = (gw & 15) * 16;
    const short* ar = A + (size_t)(r0 + l16) * 256 + quad * 8;
    const short* br = W + (size_t)(n0 + l16) * 256 + quad * 8;
    f4 acc = {};
#pragma unroll
    for (int k = 0; k < 256; k += 32)
        acc = MFMA16(*(const bf8*)(ar + k), *(const bf8*)(br + k), acc, 0, 0, 0);
    int n = n0 + l16;
    float bs = bias[n];
#pragma unroll
    for (int r = 0; r < 4; r++) {
        int row = r0 + quad * 4 + r;
        abf[(size_t)row * 512 + n] = f2bf(expf(-fmaxf(acc[r] + bs, 0.f)));
    }
}

__global__ __launch_bounds__(256) void gh_gemm(const short* __restrict__ A,
                                               const short* __restrict__ W,
                                               const float* __restrict__ bias,
                                               short* __restrict__ ghb) {
    int gw = blockIdx.x * 4 + (threadIdx.x >> 6);   // 131072 wave-tiles
    int lane = threadIdx.x & 63, l16 = lane & 15, quad = lane >> 4;
    int r0 = (gw >> 5) * 16, n0 = (gw & 31) * 16;
    const short* ar = A + (size_t)(r0 + l16) * 256 + quad * 8;
    const short* br = W + (size_t)(n0 + l16) * 256 + quad * 8;
    f4 acc = {};
#pragma unroll
    for (int k = 0; k < 256; k += 32)
        acc = MFMA16(*(const bf8*)(ar + k), *(const bf8*)(br + k), acc, 0, 0, 0);
    int n = n0 + l16;
    float bs = bias[n];
#pragma unroll
    for (int r = 0; r < 4; r++) {
        int row = r0 + quad * 4 + r;
        ghb[(size_t)row * 512 + n] = f2bf(expf(-fmaxf(acc[r] + bs, 0.f)));
    }
}

__global__ __launch_bounds__(256) void beta_gemm(const short* __restrict__ A,
                                                 const short* __restrict__ W,
                                                 const float* __restrict__ bias,
                                                 short* __restrict__ betab) {
    int gw = blockIdx.x * 4 + (threadIdx.x >> 6);   // 65536 wave-tiles, K=512
    int lane = threadIdx.x & 63, l16 = lane & 15, quad = lane >> 4;
    int r0 = (gw >> 4) * 16, n0 = (gw & 15) * 16;
    const short* ar = A + (size_t)(r0 + l16) * 512 + quad * 8;
    const short* br = W + (size_t)(n0 + l16) * 512 + quad * 8;
    f4 acc = {};
#pragma unroll
    for (int k = 0; k < 512; k += 32)
        acc = MFMA16(*(const bf8*)(ar + k), *(const bf8*)(br + k), acc, 0, 0, 0);
    int n = n0 + l16;
    float bs = bias[n];
#pragma unroll
    for (int r = 0; r < 4; r++) {
        int row = r0 + quad * 4 + r;
        betab[(size_t)row * 256 + n] = f2bf(acc[r] + bs);
    }
}

// --------------------------------------------- K1: x_hat = hid @ Wout^T
__global__ __launch_bounds__(256) void k1(const short* __restrict__ hidb,
                                          const short* __restrict__ Wo,
                                          const float* __restrict__ bout,
                                          const float* __restrict__ inp,
                                          short* __restrict__ xhatb,
                                          short* __restrict__ xcb,
                                          float* __restrict__ num, int t) {
    int gw = blockIdx.x * 4 + (threadIdx.x >> 6);   // 512 tiles: 32 b x 16 n
    int lane = threadIdx.x & 63, l16 = lane & 15, quad = lane >> 4;
    int b0 = (gw >> 4) * 16, n0 = (gw & 15) * 16;
    const short* ar = hidb + (size_t)(b0 + l16) * 512 + quad * 8;
    const short* br = Wo + (size_t)(n0 + l16) * 512 + quad * 8;
    f4 acc = {};
#pragma unroll
    for (int k = 0; k < 512; k += 32)
        acc = MFMA16(*(const bf8*)(ar + k), *(const bf8*)(br + k), acc, 0, 0, 0);
    int n = n0 + l16;
    float bs = bout[n];
    float l1 = 0.f;
#pragma unroll
    for (int r = 0; r < 4; r++) {
        int b = b0 + quad * 4 + r;
        const float* vb = inp + (size_t)b * S3TF + (size_t)t * F + n;
        float v = vb[0], m = vb[2 * TF];
        float xh = acc[r] + bs;
        l1 += fabsf(v - xh) * m;
        xhatb[(size_t)b * 256 + n] = f2bf(xh);
        xcb[(size_t)b * 256 + n] = f2bf(m * v + (1.f - m) * xh);
    }
    l1 = wsum(l1);
    __shared__ float red[4];
    if (lane == 0) red[threadIdx.x >> 6] = l1;
    __syncthreads();
    if (threadIdx.x == 0) atomicAdd(&num[t], red[0] + red[1] + red[2] + red[3]);
}

// ------------------------ K2: z_hat = x_c @ Wzm^T ; c_hat / c_c / loss2,3
__global__ __launch_bounds__(256) void k2(const short* __restrict__ xcb,
                                          const short* __restrict__ Wzm,
                                          const float* __restrict__ bz,
                                          const short* __restrict__ xhatb,
                                          const short* __restrict__ betab,
                                          const float* __restrict__ inp,
                                          float* __restrict__ out,
                                          short* __restrict__ gib,
                                          float* __restrict__ num, int t) {
    int gw = blockIdx.x * 4 + (threadIdx.x >> 6);   // 512 tiles
    int lane = threadIdx.x & 63, l16 = lane & 15, quad = lane >> 4;
    int b0 = (gw >> 4) * 16, n0 = (gw & 15) * 16;
    const short* ar = xcb + (size_t)(b0 + l16) * 256 + quad * 8;
    const short* br = Wzm + (size_t)(n0 + l16) * 256 + quad * 8;
    f4 acc = {};
#pragma unroll
    for (int k = 0; k < 256; k += 32)
        acc = MFMA16(*(const bf8*)(ar + k), *(const bf8*)(br + k), acc, 0, 0, 0);
    int n = n0 + l16;
    float bs = bz[n];
    float l2 = 0.f, l3 = 0.f;
#pragma unroll
    for (int r = 0; r < 4; r++) {
        int b = b0 + quad * 4 + r;
        const float* vb = inp + (size_t)b * S3TF + (size_t)t * F + n;
        float v = vb[0], m = vb[2 * TF];
        float zh = acc[r] + bs;
        float xh = bf2f(xhatb[(size_t)b * 256 + n]);
        float bt = bf2f(betab[((size_t)t * 512 + b) * 256 + n]);
        float ch = bt * zh + (1.f - bt) * xh;
        float cc = m * v + (1.f - m) * ch;
        out[(size_t)b * TF + (size_t)t * F + n] = ch;
        out[BTF + (size_t)b * TF + (size_t)t * F + n] = cc;
        gib[(size_t)b * 512 + n] = f2bf(cc);
        gib[(size_t)b * 512 + 256 + n] = f2bf(m);
        l2 += fabsf(v - zh) * m;
        l3 += fabsf(v - ch) * m;
    }
    l2 = wsum(l2); l3 = wsum(l3);
    __shared__ float red2[2][4];
    if (lane == 0) { red2[0][threadIdx.x >> 6] = l2; red2[1][threadIdx.x >> 6] = l3; }
    __syncthreads();
    if (threadIdx.x == 0) {
        atomicAdd(&num[128 + t], red2[0][0] + red2[0][1] + red2[0][2] + red2[0][3]);
        atomicAdd(&num[256 + t], red2[1][0] + red2[1][1] + red2[1][2] + red2[1][3]);
    }
}

// --------------------- K3: fused GRU (6 weight families) + hid update
__global__ __launch_bounds__(256) void k3(const short* __restrict__ gib,
                                          const short* __restrict__ hidb,
                                          const float* __restrict__ hidf,
                                          const short* __restrict__ Wih,
                                          const short* __restrict__ Whh,
                                          const float* __restrict__ bih,
                                          const float* __restrict__ bhh,
                                          const short* __restrict__ ghb,
                                          float* __restrict__ hidf_n,
                                          short* __restrict__ hidb_n, int t) {
    int gw = blockIdx.x * 4 + (threadIdx.x >> 6);   // 1024 tiles: 32 b x 32 j
    int lane = threadIdx.x & 63, l16 = lane & 15, quad = lane >> 4;
    int b0 = (gw >> 5) * 16, j0 = (gw & 31) * 16;
    const short* ag = gib + (size_t)(b0 + l16) * 512 + quad * 8;
    const short* ah = hidb + (size_t)(b0 + l16) * 512 + quad * 8;
    const short* w0 = Wih + (size_t)(j0 + l16) * 512 + quad * 8;
    const short* w3 = Whh + (size_t)(j0 + l16) * 512 + quad * 8;
    f4 aglr = {}, aglz = {}, agln = {}, ahlr = {}, ahlz = {}, ahln = {};
#pragma unroll
    for (int k = 0; k < 512; k += 32) {
        bf8 g = *(const bf8*)(ag + k);
        bf8 h = *(const bf8*)(ah + k);
        aglr = MFMA16(g, *(const bf8*)(w0 + k), aglr, 0, 0, 0);
        aglz = MFMA16(g, *(const bf8*)(w0 + 512 * 512 + k), aglz, 0, 0, 0);
        agln = MFMA16(g, *(const bf8*)(w0 + 1024 * 512 + k), agln, 0, 0, 0);
        ahlr = MFMA16(h, *(const bf8*)(w3 + k), ahlr, 0, 0, 0);
        ahlz = MFMA16(h, *(const bf8*)(w3 + 512 * 512 + k), ahlz, 0, 0, 0);
        ahln = MFMA16(h, *(const bf8*)(w3 + 1024 * 512 + k), ahln, 0, 0, 0);
    }
    int j = j0 + l16;
    float br = bih[j], bzg = bih[512 + j], bn = bih[1024 + j];
    float cr = bhh[j], czg = bhh[512 + j], cn = bhh[1024 + j];
#pragma unroll
    for (int r = 0; r < 4; r++) {
        int b = b0 + quad * 4 + r;
        float rg = 1.f / (1.f + expf(-(aglr[r] + br + ahlr[r] + cr)));
        float zg = 1.f / (1.f + expf(-(aglz[r] + bzg + ahlz[r] + czg)));
        float ng = tanhf(agln[r] + bn + rg * (ahln[r] + cn));
        float hold = hidf[(size_t)b * 512 + j];
        float hn = (1.f - zg) * ng + zg * hold;
        if (t + 1 < T) hn *= bf2f(ghb[((size_t)(t + 1) * 512 + b) * 512 + j]);
        hidf_n[(size_t)b * 512 + j] = hn;
        hidb_n[(size_t)b * 512 + j] = f2bf(hn);
    }
}

// ----------------------------------------------------------------- final loss
__global__ void final_k(const float* __restrict__ nd, float* __restrict__ outloss) {
    int tid = threadIdx.x;   // 128, one per t
    float v = (nd[tid] + nd[128 + tid] + nd[256 + tid]) / (nd[384 + tid] + 1e-5f);
    __shared__ float red[128];
    red[tid] = v; __syncthreads();
    for (int o = 64; o > 0; o >>= 1) { if (tid < o) red[tid] += red[tid + o]; __syncthreads(); }
    if (tid == 0) *outloss = red[0];
}

// ---------------------------------------------------------------------------
extern "C" void kernel_launch(void* const* d_in, const int* in_sizes, int n_in,
                              void* d_out, int out_size, void* d_ws, size_t ws_size,
                              hipStream_t stream) {
    const float* inp   = (const float*)d_in[0];
    const float* Wdx   = (const float*)d_in[1];
    const float* bdx   = (const float*)d_in[2];
    const float* Wdh   = (const float*)d_in[3];
    const float* bdh   = (const float*)d_in[4];
    const float* Wout  = (const float*)d_in[5];
    const float* bout  = (const float*)d_in[6];
    const float* Wz    = (const float*)d_in[7];
    const float* bz    = (const float*)d_in[8];
    const float* Wbeta = (const float*)d_in[9];
    const float* bbeta = (const float*)d_in[10];
    const float* Wih   = (const float*)d_in[11];
    const float* Whh   = (const float*)d_in[12];
    const float* bih   = (const float*)d_in[13];
    const float* bhh   = (const float*)d_in[14];
    float* out = (float*)d_out;

    char* p = (char*)d_ws;
    short* wb    = (short*)p; p += (size_t)2097152 * 2;      // all weights bf16
    short* dbf   = (short*)p; p += (size_t)16777216 * 2;     // delta bf16 [T*B,256]
    short* abf   = (short*)p; p += (size_t)33554432 * 2;     // [gamma_x | m] [T*B,512]
    short* ghb   = (short*)p; p += (size_t)33554432 * 2;     // gamma_h bf16 [T*B,512]
    short* betab = (short*)p; p += (size_t)16777216 * 2;     // beta bf16 [T*B,256]
    short* xhatb = (short*)p; p += (size_t)131072 * 2;
    short* xcb   = (short*)p; p += (size_t)131072 * 2;
    short* gib   = (short*)p; p += (size_t)262144 * 2;       // [c_c | m] [B,512]
    short* hbA   = (short*)p; p += (size_t)262144 * 2;
    short* hbB   = (short*)p; p += (size_t)262144 * 2;
    float* hfA   = (float*)p; p += (size_t)262144 * 4;
    float* hfB   = (float*)p; p += (size_t)262144 * 4;
    float* nd    = (float*)p; p += (size_t)512 * 4;          // num[384] + den[128]

    const short* Wdxb   = wb;
    const short* Wdhb   = wb + 65536;
    const short* Wzmb   = wb + 196608;
    const short* Woutb  = wb + 262144;
    const short* Wbetab = wb + 393216;
    const short* Wihb   = wb + 524288;
    const short* Whhb   = wb + 1310720;

    init_k<<<1024, 256, 0, stream>>>(hfA, hbA, nd);
    wconv_k<<<8192, 256, 0, stream>>>(Wdx, Wdh, Wz, Wout, Wbeta, Wih, Whh, wb);
    aconv_k<<<65536, 256, 0, stream>>>(inp, dbf, abf, nd + 384);
    gx_gemm<<<16384, 256, 0, stream>>>(dbf, Wdxb, bdx, abf);
    gh_gemm<<<32768, 256, 0, stream>>>(dbf, Wdhb, bdh, ghb);
    beta_gemm<<<16384, 256, 0, stream>>>(abf, Wbetab, bbeta, betab);

    for (int t = 0; t < T; ++t) {
        short* hbc = (t & 1) ? hbB : hbA;
        short* hbn = (t & 1) ? hbA : hbB;
        float* hfc = (t & 1) ? hfB : hfA;
        float* hfn = (t & 1) ? hfA : hfB;
        k1<<<128, 256, 0, stream>>>(hbc, Woutb, bout, inp, xhatb, xcb, nd, t);
        k2<<<128, 256, 0, stream>>>(xcb, Wzmb, bz, xhatb, betab, inp, out, gib, nd, t);
        k3<<<256, 256, 0, stream>>>(gib, hbc, hfc, Wihb, Whhb, bih, bhh, ghb, hfn, hbn, t);
    }
    final_k<<<1, 128, 0, stream>>>(nd, out + 2 * BTF);
}